// Round 1
// baseline (379.152 us; speedup 1.0000x reference)
//
#include <hip/hip_runtime.h>
#include <stdint.h>

#define B_ 16
#define T_ 4096
#define C_ 64
#define H_ 128
#define BQ 128
#define BK 64
#define KLS 136   // K LDS row stride (128 + 8 pad -> 4-bank row shift, 2-way = free)
#define VS  72    // Vt / P LDS row stride (64 + 8 pad)

typedef __attribute__((ext_vector_type(8))) short  short8;   // 8 bf16 = 4 VGPRs
typedef __attribute__((ext_vector_type(4))) float  floatx4;  // MFMA C/D frag

__device__ __forceinline__ unsigned short f2bf(float f) {
    union { float f; unsigned int u; } v; v.f = f;
    return (unsigned short)((v.u + 0x7fffu + ((v.u >> 16) & 1u)) >> 16);  // RNE
}

__device__ __forceinline__ float fexp2(float x) {
#if __has_builtin(__builtin_amdgcn_exp2f)
    return __builtin_amdgcn_exp2f(x);
#else
    return exp2f(x);
#endif
}

// ---------------------------------------------------------------------------
// Projections: q,k -> bf16 [B][T][H] row-major; v -> bf16 vt[B][H][T] (transposed)
// fp32 VALU compute (more accurate than bf16 MFMA for the tiny K=64 GEMM).
// ---------------------------------------------------------------------------
__global__ __launch_bounds__(256) void proj_kernel(
    const float* __restrict__ x, const float* __restrict__ Wk,
    const float* __restrict__ Wq, const float* __restrict__ Wv,
    unsigned short* __restrict__ qo, unsigned short* __restrict__ ko,
    unsigned short* __restrict__ vto)
{
    __shared__ __align__(16) char smem[48 * 1024];
    float* xl = (float*)smem;                                  // [64][64] fp32 x tile
    float* wl = (float*)(smem + 16384);                        // [64][128] fp32 W
    unsigned short* vtl = (unsigned short*)(smem + 16384);     // [128][72] bf16 (aliases wl)

    const int tid = threadIdx.x;
    const int b   = blockIdx.x >> 6;
    const int t0  = (blockIdx.x & 63) * 64;

    // stage x tile (coalesced float4)
    #pragma unroll
    for (int it = 0; it < 4; ++it) {
        int r = (tid >> 4) + it * 16;
        int c = (tid & 15) * 4;
        *(float4*)&xl[r * 64 + c] =
            *(const float4*)(x + ((size_t)(b * T_ + t0 + r)) * C_ + c);
    }

    const int h0 = (tid & 31) * 4;  // 4 consecutive head cols
    const int rg = tid >> 5;        // 8 row-groups of 8 rows

    for (int m = 0; m < 3; ++m) {
        const float* W = (m == 0) ? Wk : (m == 1) ? Wq : Wv;
        __syncthreads();
        #pragma unroll
        for (int it = 0; it < 8; ++it) {
            int r = (tid >> 5) + it * 8;
            int c = (tid & 31) * 4;
            *(float4*)&wl[r * 128 + c] = *(const float4*)(W + r * 128 + c);
        }
        __syncthreads();

        float acc[8][4];
        #pragma unroll
        for (int i = 0; i < 8; ++i)
            #pragma unroll
            for (int j = 0; j < 4; ++j) acc[i][j] = 0.f;

        for (int c = 0; c < 64; ++c) {
            float4 w = *(const float4*)&wl[c * 128 + h0];
            #pragma unroll
            for (int i = 0; i < 8; ++i) {
                float xi = xl[(rg * 8 + i) * 64 + c];   // LDS broadcast
                acc[i][0] += xi * w.x;
                acc[i][1] += xi * w.y;
                acc[i][2] += xi * w.z;
                acc[i][3] += xi * w.w;
            }
        }

        if (m < 2) {
            unsigned short* o = (m == 0) ? ko : qo;
            #pragma unroll
            for (int i = 0; i < 8; ++i) {
                ushort4 pk;
                pk.x = f2bf(acc[i][0]); pk.y = f2bf(acc[i][1]);
                pk.z = f2bf(acc[i][2]); pk.w = f2bf(acc[i][3]);
                *(ushort4*)(o + ((size_t)(b * T_ + t0 + rg * 8 + i)) * H_ + h0) = pk;
            }
        } else {
            __syncthreads();  // all waves done reading wl before aliasing it
            #pragma unroll
            for (int i = 0; i < 8; ++i)
                #pragma unroll
                for (int c2 = 0; c2 < 4; ++c2)
                    vtl[(h0 + c2) * VS + rg * 8 + i] = f2bf(acc[i][c2]);
            __syncthreads();
            int h  = tid >> 1;
            int sg = (tid & 1) * 32;
            int4* dst = (int4*)(vto + ((size_t)(b * H_ + h)) * T_ + t0 + sg);
            const int4* src = (const int4*)&vtl[h * VS + sg];
            dst[0] = src[0]; dst[1] = src[1]; dst[2] = src[2]; dst[3] = src[3];
        }
    }
}

// ---------------------------------------------------------------------------
// Flash attention, no-max softmax (logits bounded, exp2 can't overflow fp32).
// Block = 256 thr (4 waves), BQ=128 rows (wave owns 32 = 2 m-tiles), BK=64.
// mfma_f32_16x16x32_bf16: A[m=lane&15][k=quad*8+j], C/D col=lane&15,row=quad*4+reg.
// ---------------------------------------------------------------------------
__global__ __launch_bounds__(256, 2) void attn_kernel(
    const unsigned short* __restrict__ q,
    const unsigned short* __restrict__ k,
    const unsigned short* __restrict__ vt,
    float* __restrict__ out)
{
    __shared__ unsigned short Kl[64 * KLS];        // 17408 B: K chunk [64 keys][128 h]
    __shared__ unsigned short Vtl[128 * VS];       // 18432 B: V^T chunk [128 h][64 keys]
    __shared__ unsigned short Pl[4 * 32 * VS];     // 18432 B: per-wave P [32 q][64 keys]

    const int tid  = threadIdx.x;
    const int wave = tid >> 6;
    const int lane = tid & 63;
    const int col  = lane & 15;   // n-index inside a 16-tile
    const int quad = lane >> 4;   // 0..3
    const int b    = blockIdx.y;
    const int q0   = blockIdx.x * BQ;

    // Q A-fragments straight from global (read once, reused 64 chunks)
    short8 qf[2][4];
    #pragma unroll
    for (int mt = 0; mt < 2; ++mt) {
        const unsigned short* qrow =
            q + ((size_t)(b * T_ + q0 + wave * 32 + mt * 16 + col)) * H_ + quad * 8;
        #pragma unroll
        for (int ks = 0; ks < 4; ++ks)
            qf[mt][ks] = *(const short8*)(qrow + ks * 32);
    }

    floatx4 o[2][8];              // O accum [mt][ht 16-wide tiles]
    #pragma unroll
    for (int mt = 0; mt < 2; ++mt)
        #pragma unroll
        for (int ht = 0; ht < 8; ++ht) { o[mt][ht][0]=0.f; o[mt][ht][1]=0.f; o[mt][ht][2]=0.f; o[mt][ht][3]=0.f; }
    float lsum[2][4] = {{0.f,0.f,0.f,0.f},{0.f,0.f,0.f,0.f}};   // softmax denom partials

    const float SC = 0.125f * 1.44269504088896340736f;  // scale * log2(e)
    unsigned short* Pw = &Pl[wave * 32 * VS];

    for (int s0 = 0; s0 < T_; s0 += BK) {
        __syncthreads();   // prior chunk's PV reads done before restaging
        #pragma unroll
        for (int it = 0; it < 4; ++it) {      // K chunk: 64 rows x 256B coalesced
            int r = (tid >> 4) + it * 16;
            int c = (tid & 15) * 8;
            int4 d = *(const int4*)(k + ((size_t)(b * T_ + s0 + r)) * H_ + c);
            *(int4*)&Kl[r * KLS + c] = d;
        }
        #pragma unroll
        for (int it = 0; it < 4; ++it) {      // Vt chunk: 128 rows x 128B coalesced
            int r = (tid >> 3) + it * 32;
            int c = (tid & 7) * 8;
            int4 d = *(const int4*)(vt + ((size_t)(b * H_ + r)) * T_ + s0 + c);
            *(int4*)&Vtl[r * VS + c] = d;
        }
        __syncthreads();

        // S = Q K^T : per wave 2 m-tiles x 4 n-tiles, K=128 in 4 steps
        floatx4 s[2][4];
        #pragma unroll
        for (int mt = 0; mt < 2; ++mt)
            #pragma unroll
            for (int nt = 0; nt < 4; ++nt) { s[mt][nt][0]=0.f; s[mt][nt][1]=0.f; s[mt][nt][2]=0.f; s[mt][nt][3]=0.f; }
        #pragma unroll
        for (int ks = 0; ks < 4; ++ks) {
            #pragma unroll
            for (int nt = 0; nt < 4; ++nt) {
                short8 kf = *(const short8*)&Kl[(nt * 16 + col) * KLS + ks * 32 + quad * 8];
                s[0][nt] = __builtin_amdgcn_mfma_f32_16x16x32_bf16(qf[0][ks], kf, s[0][nt], 0, 0, 0);
                s[1][nt] = __builtin_amdgcn_mfma_f32_16x16x32_bf16(qf[1][ks], kf, s[1][nt], 0, 0, 0);
            }
        }

        // P = exp2(S * SC); accumulate row-sum partials; C-layout -> LDS (A-layout readback)
        #pragma unroll
        for (int mt = 0; mt < 2; ++mt)
            #pragma unroll
            for (int nt = 0; nt < 4; ++nt)
                #pragma unroll
                for (int r = 0; r < 4; ++r) {
                    float p = fexp2(s[mt][nt][r] * SC);
                    lsum[mt][r] += p;
                    Pw[(mt * 16 + quad * 4 + r) * VS + nt * 16 + col] = f2bf(p);
                }

        // O += P V  (same-wave LDS write->read: DS pipe is in-order per wave)
        #pragma unroll
        for (int ks = 0; ks < 2; ++ks) {
            short8 pf0 = *(const short8*)&Pw[(0 * 16 + col) * VS + ks * 32 + quad * 8];
            short8 pf1 = *(const short8*)&Pw[(1 * 16 + col) * VS + ks * 32 + quad * 8];
            #pragma unroll
            for (int ht = 0; ht < 8; ++ht) {
                short8 vf = *(const short8*)&Vtl[(ht * 16 + col) * VS + ks * 32 + quad * 8];
                o[0][ht] = __builtin_amdgcn_mfma_f32_16x16x32_bf16(pf0, vf, o[0][ht], 0, 0, 0);
                o[1][ht] = __builtin_amdgcn_mfma_f32_16x16x32_bf16(pf1, vf, o[1][ht], 0, 0, 0);
            }
        }
    }

    // epilogue: reduce denom across the quad's 16 lanes, normalize, store fp32
    #pragma unroll
    for (int mt = 0; mt < 2; ++mt)
        #pragma unroll
        for (int r = 0; r < 4; ++r) {
            float l = lsum[mt][r];
            l += __shfl_xor(l, 1);
            l += __shfl_xor(l, 2);
            l += __shfl_xor(l, 4);
            l += __shfl_xor(l, 8);
            float rinv = 1.0f / l;
            int row = q0 + wave * 32 + mt * 16 + quad * 4 + r;
            float* orow = out + ((size_t)(b * T_ + row)) * H_;
            #pragma unroll
            for (int ht = 0; ht < 8; ++ht)
                orow[ht * 16 + col] = o[mt][ht][r] * rinv;
        }
}

extern "C" void kernel_launch(void* const* d_in, const int* in_sizes, int n_in,
                              void* d_out, int out_size, void* d_ws, size_t ws_size,
                              hipStream_t stream)
{
    const float* x  = (const float*)d_in[0];
    const float* Wk = (const float*)d_in[1];
    const float* Wq = (const float*)d_in[2];
    const float* Wv = (const float*)d_in[3];
    float* out = (float*)d_out;

    const size_t elems = (size_t)B_ * T_ * H_;            // 8.4M elements
    unsigned short* qb  = (unsigned short*)d_ws;          // bf16 q   [B][T][H]  16 MB
    unsigned short* kb  = qb + elems;                     // bf16 k   [B][T][H]  16 MB
    unsigned short* vtb = kb + elems;                     // bf16 v^T [B][H][T]  16 MB

    proj_kernel<<<dim3(B_ * 64), dim3(256), 0, stream>>>(x, Wk, Wq, Wv, qb, kb, vtb);
    attn_kernel<<<dim3(T_ / BQ, B_), dim3(256), 0, stream>>>(qb, kb, vtb, out);
}